// Round 12
// baseline (224.827 us; speedup 1.0000x reference)
//
#include <hip/hip_runtime.h>
#include <math.h>

constexpr int BB = 2;
constexpr int SEQ = 2048;
constexpr int HD = 1024;
constexpr int DH = 64;       // head dim
constexpr int NHEAD = 8;
constexpr int D3 = 192;      // 3*DH
constexpr int KSEL = 256;    // SEQ / SPARSITY
constexpr float NEG = -1e30f;
constexpr float ROPE_C = -0.5756462732485115f;   // -ln(10000)/16

typedef short short8 __attribute__((ext_vector_type(8)));
typedef float f32x4 __attribute__((ext_vector_type(4)));

__device__ __forceinline__ ushort bf16u(float f) {
  union { float f; unsigned u; } v; v.f = f;
  unsigned r = (v.u + 0x7FFFu + ((v.u >> 16) & 1u)) >> 16;
  return (ushort)r;
}
__device__ __forceinline__ float bf2f(ushort h) {
  union { unsigned u; float f; } v; v.u = ((unsigned)h) << 16;
  return v.f;
}

// async global->LDS, 16B per lane; LDS dest = wave-uniform base + lane*16
__device__ __forceinline__ void gl_lds16(const ushort* g, ushort* l) {
  __builtin_amdgcn_global_load_lds(
      (const __attribute__((address_space(1))) unsigned int*)g,
      (__attribute__((address_space(3))) unsigned int*)l, 16, 0, 0);
}

// order-preserving composite key: rank predicate (s_j > s_i) || (s_j==s_i && j<i)
// becomes key_j > key_i  (single u64 compare)
__device__ __forceinline__ unsigned long long rankkey(float s, int idx) {
  union { float f; unsigned u; } v; v.f = s;
  unsigned o = (v.u & 0x80000000u) ? ~v.u : (v.u | 0x80000000u);
  return ((unsigned long long)o << 11) | (unsigned)(2047 - idx);
}

// ---------------- fused X cast + router scores ----------------
// 128 blocks x 256 thr; thread = (row, 128-f32 segment). X read once: bf16 cast
// stored from the same registers the router dot-products consume.
__global__ __launch_bounds__(256) void cast_router(const float* __restrict__ X,
    const float* __restrict__ rw, ushort* __restrict__ Xb, float* __restrict__ scores) {
  __shared__ float rwT[8][8][132];          // [n][seg][128+4pad]
  int tid = threadIdx.x;
  for (int idx = tid; idx < 8192; idx += 256) {
    int h = idx & 1023, n = idx >> 10;
    rwT[n][h >> 7][h & 127] = rw[h * 8 + n];
  }
  __syncthreads();
  int row = blockIdx.x * 32 + (tid >> 3);   // bt row
  int seg = tid & 7;
  const float* xrow = X + (size_t)row * HD + seg * 128;
  ushort* yrow = Xb + (size_t)row * HD + seg * 128;
  float acc[8] = {};
#pragma unroll 8
  for (int it = 0; it < 32; it++) {
    float4 xv = *(const float4*)(xrow + 4 * it);
    ushort4 cv;
    cv.x = bf16u(xv.x); cv.y = bf16u(xv.y); cv.z = bf16u(xv.z); cv.w = bf16u(xv.w);
    *(ushort4*)(yrow + 4 * it) = cv;
#pragma unroll
    for (int n = 0; n < 8; n++) {
      float4 rv = *(const float4*)&rwT[n][seg][4 * it];
      acc[n] += xv.x * rv.x + xv.y * rv.y + xv.z * rv.z + xv.w * rv.w;
    }
  }
#pragma unroll
  for (int n = 0; n < 8; n++) {
    acc[n] += __shfl_xor(acc[n], 1);
    acc[n] += __shfl_xor(acc[n], 2);
    acc[n] += __shfl_xor(acc[n], 4);
  }
  int b = row >> 11, t2 = row & (SEQ - 1);
  scores[((size_t)b * NHEAD + seg) * SEQ + t2] = acc[seg];
}

// ---------------- transpose + cast pair: W[K][N] f32 -> Wt[N][K] bf16 ----------------
__global__ __launch_bounds__(256) void transpose_cast2(
    const float* __restrict__ W1, ushort* __restrict__ T1,
    const float* __restrict__ W2, ushort* __restrict__ T2, int K, int N) {
  const float* W = blockIdx.z ? W2 : W1;
  ushort* Wt = blockIdx.z ? T2 : T1;
  __shared__ float tile[32][33];
  int n0 = blockIdx.x * 32, k0 = blockIdx.y * 32;
  int tx = threadIdx.x & 31, ty = threadIdx.x >> 5;
#pragma unroll
  for (int i = 0; i < 4; i++)
    tile[ty + 8 * i][tx] = W[(size_t)(k0 + ty + 8 * i) * N + n0 + tx];
  __syncthreads();
#pragma unroll
  for (int i = 0; i < 4; i++)
    Wt[(size_t)(n0 + ty + 8 * i) * K + k0 + tx] = bf16u(tile[tx][ty + 8 * i]);
}

// ---------------- top-k stage 1: u64-key partial rank counts (16 chunks of 128) --------
__global__ __launch_bounds__(256) void topk_partial(const float* __restrict__ scores,
    int* __restrict__ pranks) {
  int row = blockIdx.x;                      // 16
  int c = blockIdx.y;                        // 16 chunks of 128 j
  __shared__ unsigned long long ck[128];
  const float* sp = scores + (size_t)row * SEQ;
  int tid = threadIdx.x;
  if (tid < 128) ck[tid] = rankkey(sp[c * 128 + tid], c * 128 + tid);
  __syncthreads();
  unsigned long long kv[8]; int p[8];
#pragma unroll
  for (int i = 0; i < 8; i++) {
    int vi = i * 256 + tid;
    kv[i] = rankkey(sp[vi], vi);
    p[i] = 0;
  }
#pragma unroll 8
  for (int j = 0; j < 128; j += 2) {
    unsigned long long k0 = ck[j], k1 = ck[j + 1];
#pragma unroll
    for (int i = 0; i < 8; i++) {
      p[i] += (k0 > kv[i]);
      p[i] += (k1 > kv[i]);
    }
  }
#pragma unroll
  for (int i = 0; i < 8; i++)
    pranks[((size_t)row * 16 + c) * SEQ + i * 256 + tid] = p[i];
}

// ---------------- top-k stage 2: sum partials, ballot-scan, emit ----------------
__global__ __launch_bounds__(1024) void topk_select(const float* __restrict__ scores,
    const int* __restrict__ pranks, int* __restrict__ sel, float* __restrict__ gates) {
  int bn = blockIdx.x;
  __shared__ int wsum[16];
  int tid = threadIdx.x;
  int t0 = tid * 2;
  int r0 = 0, r1 = 0;
#pragma unroll
  for (int c = 0; c < 16; c++) {
    const int2 pp = *(const int2*)&pranks[((size_t)bn * 16 + c) * SEQ + t0];
    r0 += pp.x; r1 += pp.y;
  }
  int f0 = r0 < KSEL, f1 = r1 < KSEL;
  unsigned long long b0 = __ballot(f0), b1 = __ballot(f1);
  int lane = tid & 63, wv = tid >> 6;
  unsigned long long lower = (1ULL << lane) - 1ULL;
  int before = __popcll(b0 & lower) + __popcll(b1 & lower);
  int wtotal = __popcll(b0) + __popcll(b1);
  if (lane == 0) wsum[wv] = wtotal;
  __syncthreads();
  int woff = 0;
#pragma unroll
  for (int i2 = 0; i2 < 16; i2++) woff += (i2 < wv) ? wsum[i2] : 0;
  int base = woff + before;
  if (f0) { sel[bn * KSEL + base] = t0;
            gates[bn * KSEL + base] = 1.f / (1.f + __expf(-scores[(size_t)bn * SEQ + t0]));
            base++; }
  if (f1) { sel[bn * KSEL + base] = t0 + 1;
            gates[bn * KSEL + base] = 1.f / (1.f + __expf(-scores[(size_t)bn * SEQ + t0 + 1])); }
}

// ---------------- mosa qkv: gathered-A bf16 MFMA GEMM, fused RoPE -> split layouts ------
__global__ __launch_bounds__(256) void gemm_mosa_bf16(const ushort* __restrict__ Xb,
    const ushort* __restrict__ Wt, const int* __restrict__ sel,
    ushort* __restrict__ Qmg, ushort* __restrict__ Kmg, ushort* __restrict__ Vtmg) {
  __shared__ __align__(16) ushort As[64][40];
  __shared__ __align__(16) ushort Bs[64][40];
  int bn = blockIdx.x;
  int m0 = blockIdx.y * 64, n0 = blockIdx.z * 64;
  int b = bn >> 3, n = bn & 7;
  int tid = threadIdx.x;
  int lane = tid & 63, w = tid >> 6;
  int wm = w & 1, wn = w >> 1;
  int cc = lane & 15, quad = lane >> 4;
  int sr = tid >> 2, sc4 = tid & 3;

  int grow = sel[bn * KSEL + m0 + sr];
  const ushort* arow = Xb + ((size_t)(b * SEQ) + grow) * HD;
  const ushort* brow = Wt + ((size_t)(n * D3 + n0 + sr)) * HD;

  f32x4 acc[2][2];
#pragma unroll
  for (int i = 0; i < 2; i++)
#pragma unroll
    for (int j = 0; j < 2; j++)
#pragma unroll
      for (int r = 0; r < 4; r++) acc[i][j][r] = 0.f;

  for (int k0 = 0; k0 < HD; k0 += 32) {
    __syncthreads();
    *(short8*)&As[sr][8 * sc4] = *(const short8*)(arow + k0 + 8 * sc4);
    *(short8*)&Bs[sr][8 * sc4] = *(const short8*)(brow + k0 + 8 * sc4);
    __syncthreads();
    short8 af[2], bf_[2];
#pragma unroll
    for (int i = 0; i < 2; i++) af[i] = *(const short8*)&As[32 * wm + 16 * i + cc][8 * quad];
#pragma unroll
    for (int j = 0; j < 2; j++) bf_[j] = *(const short8*)&Bs[32 * wn + 16 * j + cc][8 * quad];
#pragma unroll
    for (int i = 0; i < 2; i++)
#pragma unroll
      for (int j = 0; j < 2; j++)
        acc[i][j] = __builtin_amdgcn_mfma_f32_16x16x32_bf16(af[i], bf_[j], acc[i][j], 0, 0, 0);
  }

  int bs = n0 + 32 * wn;                 // band start: 0(Qrot),32,64(Krot),96,128+,160
  // fused RoPE: pair = (acc[i][0], acc[i][1]) = dims (cc, cc+16), pos = sel[row]
  if (bs == 0 || bs == 64) {
    float inv = __expf((float)cc * ROPE_C);
#pragma unroll
    for (int i = 0; i < 2; i++) {
      int row0 = m0 + 32 * wm + 16 * i + 4 * quad;
#pragma unroll
      for (int r = 0; r < 4; r++) {
        float pos = (float)sel[bn * KSEL + row0 + r];
        float ang = pos * inv;
        float cs = cosf(ang), sn = sinf(ang);
        float x1 = acc[i][0][r], x2 = acc[i][1][r];
        acc[i][0][r] = x1 * cs - x2 * sn;
        acc[i][1][r] = x1 * sn + x2 * cs;
      }
    }
  }

#pragma unroll
  for (int i = 0; i < 2; i++)
#pragma unroll
    for (int j = 0; j < 2; j++) {
      int col = bs + 16 * j + cc;
      int row0 = m0 + 32 * wm + 16 * i + 4 * quad;
      if (col < 64) {
#pragma unroll
        for (int r = 0; r < 4; r++)
          Qmg[((size_t)bn * KSEL + row0 + r) * 64 + col] = bf16u(acc[i][j][r] * 0.125f);
      } else if (col < 128) {
#pragma unroll
        for (int r = 0; r < 4; r++)
          Kmg[((size_t)bn * KSEL + row0 + r) * 64 + (col - 64)] = bf16u(acc[i][j][r]);
      } else {
        ushort4 pk;
        pk.x = bf16u(acc[i][j][0]); pk.y = bf16u(acc[i][j][1]);
        pk.z = bf16u(acc[i][j][2]); pk.w = bf16u(acc[i][j][3]);
        *(ushort4*)&Vtmg[((size_t)bn * 64 + (col - 128)) * KSEL + row0] = pk;
      }
    }
}

// ---------------- flash6: split-K flash attention ----------------
// bx in [0,2048): dense, bn=bx&15, qt=(bx>>4)&31, chunk=bx>>9; chunk c handles
// kt = c, c+4, ... (strided -> inherently balanced, <=8 tiles critical path).
// Partial (unnormalized O bf16, m/l f32) to Opart/Mlp; flash_merge combines.
// bx in [2048,2112): mosa, direct gated scatter to avm (<=4 tiles).
__global__ __launch_bounds__(256) void flash6(
    const ushort* __restrict__ Qg, const ushort* __restrict__ Kg,
    const ushort* __restrict__ Vtg,
    const ushort* __restrict__ Qmg, const ushort* __restrict__ Kmg,
    const ushort* __restrict__ Vtmg,
    const int* __restrict__ sel, const float* __restrict__ gates,
    ushort* __restrict__ Opart, float2* __restrict__ Mlp,
    ushort* __restrict__ avm) {
  __shared__ __align__(16) ushort Ks[2][64][64];
  __shared__ __align__(16) ushort Vt[2][64][64];
  __shared__ __align__(16) ushort Ps[64][64];

  int bx = blockIdx.x;
  bool mosa = bx >= 2048;
  int bn, qt, T, kstart, kstride;
  const ushort *Qb, *Kb, *Vb;
  if (!mosa) {
    bn = bx & 15; qt = (bx >> 4) & 31;
    kstart = bx >> 9; kstride = 4; T = SEQ;
    Qb = Qg + (size_t)bn * SEQ * 64;
    Kb = Kg + (size_t)bn * SEQ * 64;
    Vb = Vtg + (size_t)bn * 64 * SEQ;
  } else {
    int rr = bx - 2048;
    bn = rr & 15; qt = 3 - (rr >> 4);
    kstart = 0; kstride = 1; T = KSEL;
    Qb = Qmg + (size_t)bn * KSEL * 64;
    Kb = Kmg + (size_t)bn * KSEL * 64;
    Vb = Vtmg + (size_t)bn * 64 * KSEL;
  }
  int b = bn >> 3, n = bn & 7;
  int tid = threadIdx.x;
  int lane = tid & 63, w = tid >> 6;
  int cc = lane & 15, quad = lane >> 4;
  int qrow = 16 * w + cc;

  // Q fragments straight from global (pre-scaled by 1/8 upstream); loop-invariant
  short8 bq[2];
  {
    const ushort* qsrc = Qb + (size_t)(qt * 64 + qrow) * 64;
    bq[0] = *(const short8*)(qsrc + 8 * quad);
    bq[1] = *(const short8*)(qsrc + 8 * (quad + 4));
  }

  // staging addresses: slice = 8 rows x 128B per wave-instr; lane l -> row +(l>>3),
  // phys chunk l&7 holds logical chunk (l&7)^(row&7)  (xor swizzle inverse)
  int rloc = lane >> 3;
  int c_log = (lane & 7) ^ rloc;
  int row0 = 16 * w + rloc, row1 = row0 + 8;
  const ushort* pK0 = Kb + (size_t)row0 * 64 + 8 * c_log;
  const ushort* pK1 = Kb + (size_t)row1 * 64 + 8 * c_log;
  const ushort* pV0 = Vb + (size_t)row0 * T + 8 * c_log;
  const ushort* pV1 = Vb + (size_t)row1 * T + 8 * c_log;

  f32x4 oacc[4];
  float m = NEG, l = 0.f;
#pragma unroll
  for (int jd = 0; jd < 4; jd++)
#pragma unroll
    for (int r = 0; r < 4; r++) oacc[jd][r] = 0.f;

  if (kstart <= qt) {
    gl_lds16(pK0 + (size_t)kstart * 4096, &Ks[0][16 * w][0]);
    gl_lds16(pK1 + (size_t)kstart * 4096, &Ks[0][16 * w + 8][0]);
    gl_lds16(pV0 + kstart * 64, &Vt[0][16 * w][0]);
    gl_lds16(pV1 + kstart * 64, &Vt[0][16 * w + 8][0]);
  }

  int it = 0;
  for (int kt = kstart; kt <= qt; kt += kstride, it++) {
    int buf = it & 1;
    __syncthreads();          // implicit vmcnt(0): buf's loads complete; prev buf free
    int nk = kt + kstride;
    if (nk <= qt) {
      int nb = buf ^ 1;
      gl_lds16(pK0 + (size_t)nk * 4096, &Ks[nb][16 * w][0]);
      gl_lds16(pK1 + (size_t)nk * 4096, &Ks[nb][16 * w + 8][0]);
      gl_lds16(pV0 + nk * 64, &Vt[nb][16 * w][0]);
      gl_lds16(pV1 + nk * 64, &Vt[nb][16 * w + 8][0]);
    }

    // S^T = K.Q^T : C col = q (cc), row = key (16j + 4quad + r)
    f32x4 sacc[4];
#pragma unroll
    for (int j = 0; j < 4; j++)
#pragma unroll
      for (int r = 0; r < 4; r++) sacc[j][r] = 0.f;
#pragma unroll
    for (int ks = 0; ks < 2; ks++) {
#pragma unroll
      for (int j = 0; j < 4; j++) {
        int krow = 16 * j + cc;
        short8 ak = *(const short8*)&Ks[buf][krow][8 * ((quad + 4 * ks) ^ (krow & 7))];
        sacc[j] = __builtin_amdgcn_mfma_f32_16x16x32_bf16(ak, bq[ks], sacc[j], 0, 0, 0);
      }
    }
    if (kt == qt) {
#pragma unroll
      for (int j = 0; j < 4; j++)
#pragma unroll
        for (int r = 0; r < 4; r++)
          if (16 * j + 4 * quad + r > qrow) sacc[j][r] = NEG;
    }
    // per-lane online softmax (q = 16w+cc fixed per lane)
    float mx = NEG;
#pragma unroll
    for (int j = 0; j < 4; j++)
#pragma unroll
      for (int r = 0; r < 4; r++) mx = fmaxf(mx, sacc[j][r]);
    mx = fmaxf(mx, __shfl_xor(mx, 16));
    mx = fmaxf(mx, __shfl_xor(mx, 32));
    float mn = fmaxf(m, mx);
    float sc = __expf(m - mn);
    m = mn;
    float rsum = 0.f;
    float p[4][4];
#pragma unroll
    for (int j = 0; j < 4; j++)
#pragma unroll
      for (int r = 0; r < 4; r++) { p[j][r] = __expf(sacc[j][r] - mn); rsum += p[j][r]; }
    rsum += __shfl_xor(rsum, 16);
    rsum += __shfl_xor(rsum, 32);
    l = l * sc + rsum;
    // Ps[q][key] packed b64 (wave-local rows)
#pragma unroll
    for (int j = 0; j < 4; j++) {
      ushort4 pk;
      pk.x = bf16u(p[j][0]); pk.y = bf16u(p[j][1]);
      pk.z = bf16u(p[j][2]); pk.w = bf16u(p[j][3]);
      int phys = (2 * j + (quad >> 1)) ^ (qrow & 7);
      *(ushort4*)&Ps[qrow][phys * 8 + 4 * (quad & 1)] = pk;
    }
    // rescale O rows (q-local = 4quad+r) by that q's sc
#pragma unroll
    for (int r = 0; r < 4; r++) {
      float scr = __shfl(sc, 16 * quad + 4 * quad + r);
#pragma unroll
      for (int jd = 0; jd < 4; jd++) oacc[jd][r] *= scr;
    }
    __asm__ volatile("s_waitcnt lgkmcnt(0)" ::: "memory");
    // O += P.V
#pragma unroll
    for (int ks = 0; ks < 2; ks++) {
      short8 ap = *(const short8*)&Ps[qrow][8 * ((quad + 4 * ks) ^ (qrow & 7))];
#pragma unroll
      for (int jd = 0; jd < 4; jd++) {
        int vrow = 16 * jd + cc;
        short8 bv = *(const short8*)&Vt[buf][vrow][8 * ((quad + 4 * ks) ^ (vrow & 7))];
        oacc[jd] = __builtin_amdgcn_mfma_f32_16x16x32_bf16(ap, bv, oacc[jd], 0, 0, 0);
      }
    }
  }

  if (!mosa) {
    size_t pb = ((size_t)(bn * 32 + qt) * 4 + (size_t)(kstart));
    ushort* obase = Opart + pb * 4096;
#pragma unroll
    for (int r = 0; r < 4; r++) {
      int ql = 16 * w + 4 * quad + r;
#pragma unroll
      for (int jd = 0; jd < 4; jd++)
        obase[ql * 64 + 16 * jd + cc] = bf16u(oacc[jd][r]);
    }
    if (quad == 0) Mlp[pb * 64 + qrow] = make_float2(m, l);
  } else {
#pragma unroll
    for (int r = 0; r < 4; r++) {
      float lr = __shfl(l, 16 * quad + 4 * quad + r);
      int q = qt * 64 + 16 * w + 4 * quad + r;
      int trow = sel[bn * KSEL + q];
      float scale = gates[bn * KSEL + q] / lr;
      size_t row = (size_t)(b * SEQ + trow);
      ushort* orow = avm + row * (NHEAD * DH) + n * DH;
#pragma unroll
      for (int jd = 0; jd < 4; jd++)
        orow[16 * jd + cc] = bf16u(oacc[jd][r] * scale);
    }
  }
}

// ---------------- merge 4 split-K partials -> avd ----------------
__global__ __launch_bounds__(256) void flash_merge(const ushort* __restrict__ Opart,
    const float2* __restrict__ Mlp, ushort* __restrict__ avd) {
  int bq = blockIdx.x;            // bn*32 + qt
  int bn = bq >> 5, qt = bq & 31;
  int b = bn >> 3, n = bn & 7;
  int tid = threadIdx.x;
  int q = tid >> 2, ds = (tid & 3) * 16;
  size_t pb = (size_t)bq * 4;
  float2 ml[4];
#pragma unroll
  for (int c = 0; c < 4; c++) ml[c] = Mlp[(pb + c) * 64 + q];
  float M = fmaxf(fmaxf(ml[0].x, ml[1].x), fmaxf(ml[2].x, ml[3].x));
  float wgt[4], L = 0.f;
#pragma unroll
  for (int c = 0; c < 4; c++) { wgt[c] = __expf(ml[c].x - M); L += wgt[c] * ml[c].y; }
  float inv = 1.f / L;
  float acc[16] = {};
#pragma unroll
  for (int c = 0; c < 4; c++) {
    const ushort* op = Opart + (pb + c) * 4096 + q * 64 + ds;
#pragma unroll
    for (int d = 0; d < 16; d++) acc[d] += wgt[c] * bf2f(op[d]);
  }
  ushort* orow = avd + ((size_t)(b * SEQ + qt * 64 + q)) * (NHEAD * DH) + n * DH + ds;
#pragma unroll
  for (int d = 0; d < 16; d++) orow[d] = bf16u(acc[d] * inv);
}

// ---------------- bf16 MFMA GEMM, 128x128 tile, BK=32, async gl_lds staging ----------
// MODE 0: out f32 = A1@B1 + A2@B2.  MODE 1: dense-qkv + fused RoPE -> Qg/Kg/Vtg.
template <int MODE>
__global__ __launch_bounds__(256) void gemm_bf16(
    const ushort* __restrict__ A1, const ushort* __restrict__ B1t, int K1,
    const ushort* __restrict__ A2, const ushort* __restrict__ B2t, int K2,
    void* __restrict__ outv, int N,
    ushort* __restrict__ Qo, ushort* __restrict__ Ko, ushort* __restrict__ Vto) {
  __shared__ __align__(16) ushort As[128][32];
  __shared__ __align__(16) ushort Bs[128][32];
  int m0 = blockIdx.x * 128, n0 = blockIdx.y * 128;
  int tid = threadIdx.x;
  int lane = tid & 63, wave = tid >> 6;
  int wm = wave & 1, wn = wave >> 1;
  int cc = lane & 15, quad = lane >> 4;

  int srow = 16 * wave + (lane >> 2);
  int c_log = ((lane & 3) - (lane >> 3)) & 3;

  f32x4 acc[4][4];
#pragma unroll
  for (int i = 0; i < 4; i++)
#pragma unroll
    for (int j = 0; j < 4; j++)
#pragma unroll
      for (int r = 0; r < 4; r++) acc[i][j][r] = 0.f;

  const int npass = (MODE == 0) ? 2 : 1;
  for (int pass = 0; pass < npass; pass++) {
    const ushort* A = pass ? A2 : A1;
    const ushort* Bt = pass ? B2t : B1t;
    int K = pass ? K2 : K1;
    const ushort* pA0 = A + (size_t)(m0 + srow) * K + 8 * c_log;
    const ushort* pA1 = A + (size_t)(m0 + srow + 64) * K + 8 * c_log;
    const ushort* pB0 = Bt + (size_t)(n0 + srow) * K + 8 * c_log;
    const ushort* pB1 = Bt + (size_t)(n0 + srow + 64) * K + 8 * c_log;
    for (int k0 = 0; k0 < K; k0 += 32) {
      __syncthreads();
      gl_lds16(pA0 + k0, &As[16 * wave][0]);
      gl_lds16(pA1 + k0, &As[16 * wave + 64][0]);
      gl_lds16(pB0 + k0, &Bs[16 * wave][0]);
      gl_lds16(pB1 + k0, &Bs[16 * wave + 64][0]);
      __syncthreads();
      short8 af[4], bfr[4];
#pragma unroll
      for (int i = 0; i < 4; i++) {
        int ra = 64 * wm + 16 * i + cc;
        af[i] = *(const short8*)&As[ra][8 * ((quad + (ra >> 1)) & 3)];
      }
#pragma unroll
      for (int j = 0; j < 4; j++) {
        int rb = 64 * wn + 16 * j + cc;
        bfr[j] = *(const short8*)&Bs[rb][8 * ((quad + (rb >> 1)) & 3)];
      }
#pragma unroll
      for (int i = 0; i < 4; i++)
#pragma unroll
        for (int j = 0; j < 4; j++)
          acc[i][j] = __builtin_amdgcn_mfma_f32_16x16x32_bf16(af[i], bfr[j], acc[i][j], 0, 0, 0);
    }
  }

  if (MODE == 1) {
    // fused RoPE: band start bs=(n0+64*wn)%192 in {0(Q),64(K),128(V)};
    // pair = (acc[i][0], acc[i][1]) = dims (cc, cc+16); pos = t = row & 2047
    int bs = (n0 + 64 * wn) % 192;
    if (bs < 128) {
      float inv = __expf((float)cc * ROPE_C);
#pragma unroll
      for (int i = 0; i < 4; i++) {
        int row0 = m0 + 64 * wm + 16 * i + 4 * quad;
#pragma unroll
        for (int r = 0; r < 4; r++) {
          float pos = (float)((row0 + r) & (SEQ - 1));
          float ang = pos * inv;
          float cs = cosf(ang), sn = sinf(ang);
          float x1 = acc[i][0][r], x2 = acc[i][1][r];
          acc[i][0][r] = x1 * cs - x2 * sn;
          acc[i][1][r] = x1 * sn + x2 * cs;
        }
      }
    }
  }

#pragma unroll
  for (int i = 0; i < 4; i++) {
#pragma unroll
    for (int j = 0; j < 4; j++) {
      int colg = n0 + 64 * wn + 16 * j + cc;
      int row0 = m0 + 64 * wm + 16 * i + 4 * quad;
      if (MODE == 0) {
#pragma unroll
        for (int r = 0; r < 4; r++)
          ((float*)outv)[(size_t)(row0 + r) * N + colg] = acc[i][j][r];
      } else {
        int nn = colg / 192, c = colg % 192;
        int b2 = row0 >> 11, t2 = row0 & 2047;
        int bn2 = b2 * 8 + nn;
        if (c < 64) {
#pragma unroll
          for (int r = 0; r < 4; r++)
            Qo[((size_t)bn2 * SEQ + t2 + r) * 64 + c] = bf16u(acc[i][j][r] * 0.125f);
        } else if (c < 128) {
#pragma unroll
          for (int r = 0; r < 4; r++)
            Ko[((size_t)bn2 * SEQ + t2 + r) * 64 + (c - 64)] = bf16u(acc[i][j][r]);
        } else {
          ushort4 pk;
          pk.x = bf16u(acc[i][j][0]); pk.y = bf16u(acc[i][j][1]);
          pk.z = bf16u(acc[i][j][2]); pk.w = bf16u(acc[i][j][3]);
          *(ushort4*)&Vto[((size_t)bn2 * 64 + (c - 128)) * SEQ + t2] = pk;
        }
      }
    }
  }
}

extern "C" void kernel_launch(void* const* d_in, const int* in_sizes, int n_in,
                              void* d_out, int out_size, void* d_ws, size_t ws_size,
                              hipStream_t stream) {
  const float* X          = (const float*)d_in[0];
  const float* router_w   = (const float*)d_in[1];
  const float* mosa_wqkv  = (const float*)d_in[2];
  const float* mosa_wo    = (const float*)d_in[3];
  const float* dense_wqkv = (const float*)d_in[4];
  const float* dense_wo   = (const float*)d_in[5];
  float* out = (float*)d_out;
  char* ws = (char*)d_ws;

  // workspace layout (bytes)
  float*  scores  = (float*) (ws + 0);          // 131072
  int*    sel     = (int*)   (ws + 131072);     // 16384
  float*  gates   = (float*) (ws + 147456);     // 16384
  ushort* avm     = (ushort*)(ws + 163840);     // 4194304
  ushort* avd     = (ushort*)(ws + 4358144);    // 4194304
  ushort* Xb      = (ushort*)(ws + 8552448);    // 8388608
  ushort* Wqkv_t  = (ushort*)(ws + 16941056);   // 3145728
  ushort* Wmq_t   = (ushort*)(ws + 20086784);   // 3145728
  ushort* Wdo_t   = (ushort*)(ws + 23232512);   // 1048576
  ushort* Wmo_t   = (ushort*)(ws + 24281088);   // 1048576
  ushort* Qg      = (ushort*)(ws + 25329664);   // 4194304  (16 bn x 2048 x 64)
  ushort* Kg      = (ushort*)(ws + 29523968);   // 4194304
  ushort* Vtg     = (ushort*)(ws + 33718272);   // 4194304  (16 bn x 64 x 2048)
  ushort* Qmg     = (ushort*)(ws + 37912576);   // 524288   (16 bn x 256 x 64)
  ushort* Kmg     = (ushort*)(ws + 38436864);   // 524288
  ushort* Vtmg    = (ushort*)(ws + 38961152);   // 524288
  int*    pranks  = (int*)   (ws + 39485440);   // 16*16*2048*4 = 2097152
  ushort* Opart   = (ushort*)(ws + 41582592);   // 16*32*4*4096*2 = 16777216
  float2* Mlp     = (float2*)(ws + 58359808);   // 16*32*4*64*8   = 2097152 (end 60456960)

  hipMemsetAsync(avm, 0, (size_t)BB * SEQ * NHEAD * DH * sizeof(ushort), stream);

  // fused X cast + router; weight transposes
  cast_router<<<BB * SEQ / 32, 256, 0, stream>>>(X, router_w, Xb, scores);
  transpose_cast2<<<dim3(48, 32, 2), 256, 0, stream>>>(dense_wqkv, Wqkv_t,
                                                       mosa_wqkv, Wmq_t, 1024, 1536);
  transpose_cast2<<<dim3(32, 16, 2), 256, 0, stream>>>(dense_wo, Wdo_t,
                                                       mosa_wo, Wmo_t, 512, 1024);

  // top-k
  topk_partial<<<dim3(BB * NHEAD, 16), 256, 0, stream>>>(scores, pranks);
  topk_select<<<BB * NHEAD, 1024, 0, stream>>>(scores, pranks, sel, gates);

  // qkv projections with fused RoPE (mosa gathered + dense)
  gemm_mosa_bf16<<<dim3(BB * NHEAD, KSEL / 64, D3 / 64), 256, 0, stream>>>(
      Xb, Wmq_t, sel, Qmg, Kmg, Vtmg);
  gemm_bf16<1><<<dim3(32, 12), 256, 0, stream>>>(Xb, Wqkv_t, 1024,
      (const ushort*)nullptr, (const ushort*)nullptr, 0, nullptr, NHEAD * D3,
      Qg, Kg, Vtg);

  // split-K flash attention (dense 2048 chunk-blocks + mosa 64) + merge
  flash6<<<2112, 256, 0, stream>>>(Qg, Kg, Vtg, Qmg, Kmg, Vtmg, sel, gates,
                                   Opart, Mlp, avm);
  flash_merge<<<512, 256, 0, stream>>>(Opart, Mlp, avd);

  // final: out = avm@mosa_wo + avd@dense_wo  (f32 out)
  gemm_bf16<0><<<dim3(32, 8), 256, 0, stream>>>(avm, Wmo_t, 512, avd, Wdo_t, 512, out, HD,
                                                nullptr, nullptr, nullptr);
}

// Round 13
// 213.918 us; speedup vs baseline: 1.0510x; 1.0510x over previous
//
#include <hip/hip_runtime.h>
#include <math.h>

constexpr int BB = 2;
constexpr int SEQ = 2048;
constexpr int HD = 1024;
constexpr int DH = 64;       // head dim
constexpr int NHEAD = 8;
constexpr int D3 = 192;      // 3*DH
constexpr int KSEL = 256;    // SEQ / SPARSITY
constexpr float NEG = -1e30f;
constexpr float ROPE_C = -0.5756462732485115f;   // -ln(10000)/16

typedef short short8 __attribute__((ext_vector_type(8)));
typedef float f32x4 __attribute__((ext_vector_type(4)));

__device__ __forceinline__ ushort bf16u(float f) {
  union { float f; unsigned u; } v; v.f = f;
  unsigned r = (v.u + 0x7FFFu + ((v.u >> 16) & 1u)) >> 16;
  return (ushort)r;
}
__device__ __forceinline__ float bf2f(ushort h) {
  union { unsigned u; float f; } v; v.u = ((unsigned)h) << 16;
  return v.f;
}

// async global->LDS, 16B per lane; LDS dest = wave-uniform base + lane*16
__device__ __forceinline__ void gl_lds16(const ushort* g, ushort* l) {
  __builtin_amdgcn_global_load_lds(
      (const __attribute__((address_space(1))) unsigned int*)g,
      (__attribute__((address_space(3))) unsigned int*)l, 16, 0, 0);
}

// order-preserving composite key: rank predicate (s_j > s_i) || (s_j==s_i && j<i)
// becomes key_j > key_i  (single u64 compare)
__device__ __forceinline__ unsigned long long rankkey(float s, int idx) {
  union { float f; unsigned u; } v; v.f = s;
  unsigned o = (v.u & 0x80000000u) ? ~v.u : (v.u | 0x80000000u);
  return ((unsigned long long)o << 11) | (unsigned)(2047 - idx);
}

// ---------------- fused X cast + router scores + avm zero ----------------
__global__ __launch_bounds__(256) void cast_router(const float* __restrict__ X,
    const float* __restrict__ rw, ushort* __restrict__ Xb, float* __restrict__ scores,
    ushort* __restrict__ avm) {
  __shared__ float rwT[8][8][132];          // [n][seg][128+4pad]
  int tid = threadIdx.x;
  // zero avm: 262144 uint4 over 32768 threads
  {
    uint4* az = (uint4*)avm;
    int gid = blockIdx.x * 256 + tid;
    uint4 z = make_uint4(0, 0, 0, 0);
#pragma unroll
    for (int i = 0; i < 8; i++) az[gid + 32768 * i] = z;
  }
  for (int idx = tid; idx < 8192; idx += 256) {
    int h = idx & 1023, n = idx >> 10;
    rwT[n][h >> 7][h & 127] = rw[h * 8 + n];
  }
  __syncthreads();
  int row = blockIdx.x * 32 + (tid >> 3);   // bt row
  int seg = tid & 7;
  const float* xrow = X + (size_t)row * HD + seg * 128;
  ushort* yrow = Xb + (size_t)row * HD + seg * 128;
  float acc[8] = {};
#pragma unroll 8
  for (int it = 0; it < 32; it++) {
    float4 xv = *(const float4*)(xrow + 4 * it);
    ushort4 cv;
    cv.x = bf16u(xv.x); cv.y = bf16u(xv.y); cv.z = bf16u(xv.z); cv.w = bf16u(xv.w);
    *(ushort4*)(yrow + 4 * it) = cv;
#pragma unroll
    for (int n = 0; n < 8; n++) {
      float4 rv = *(const float4*)&rwT[n][seg][4 * it];
      acc[n] += xv.x * rv.x + xv.y * rv.y + xv.z * rv.z + xv.w * rv.w;
    }
  }
#pragma unroll
  for (int n = 0; n < 8; n++) {
    acc[n] += __shfl_xor(acc[n], 1);
    acc[n] += __shfl_xor(acc[n], 2);
    acc[n] += __shfl_xor(acc[n], 4);
  }
  int b = row >> 11, t2 = row & (SEQ - 1);
  scores[((size_t)b * NHEAD + seg) * SEQ + t2] = acc[seg];
}

// ---------------- transpose + cast, 4 weights in one launch ----------------
__global__ __launch_bounds__(256) void transpose_cast4(
    const float* __restrict__ W0, ushort* __restrict__ T0,
    const float* __restrict__ W1, ushort* __restrict__ T1,
    const float* __restrict__ W2, ushort* __restrict__ T2,
    const float* __restrict__ W3, ushort* __restrict__ T3) {
  int z = blockIdx.z;
  const float* W; ushort* Wt; int K, N;
  if (z == 0)      { W = W0; Wt = T0; K = 1024; N = 1536; }
  else if (z == 1) { W = W1; Wt = T1; K = 1024; N = 1536; }
  else if (z == 2) { W = W2; Wt = T2; K = 512;  N = 1024; }
  else             { W = W3; Wt = T3; K = 512;  N = 1024; }
  int n0 = blockIdx.x * 32, k0 = blockIdx.y * 32;
  if (n0 >= N || k0 >= K) return;
  __shared__ float tile[32][33];
  int tx = threadIdx.x & 31, ty = threadIdx.x >> 5;
#pragma unroll
  for (int i = 0; i < 4; i++)
    tile[ty + 8 * i][tx] = W[(size_t)(k0 + ty + 8 * i) * N + n0 + tx];
  __syncthreads();
#pragma unroll
  for (int i = 0; i < 4; i++)
    Wt[(size_t)(n0 + ty + 8 * i) * K + k0 + tx] = bf16u(tile[tx][ty + 8 * i]);
}

// ---------------- top-k stage 1: u64-key partial rank counts (16 chunks of 128) --------
__global__ __launch_bounds__(256) void topk_partial(const float* __restrict__ scores,
    int* __restrict__ pranks) {
  int row = blockIdx.x;                      // 16
  int c = blockIdx.y;                        // 16 chunks of 128 j
  __shared__ unsigned long long ck[128];
  const float* sp = scores + (size_t)row * SEQ;
  int tid = threadIdx.x;
  if (tid < 128) ck[tid] = rankkey(sp[c * 128 + tid], c * 128 + tid);
  __syncthreads();
  unsigned long long kv[8]; int p[8];
#pragma unroll
  for (int i = 0; i < 8; i++) {
    int vi = i * 256 + tid;
    kv[i] = rankkey(sp[vi], vi);
    p[i] = 0;
  }
#pragma unroll 8
  for (int j = 0; j < 128; j += 2) {
    unsigned long long k0 = ck[j], k1 = ck[j + 1];
#pragma unroll
    for (int i = 0; i < 8; i++) {
      p[i] += (k0 > kv[i]);
      p[i] += (k1 > kv[i]);
    }
  }
#pragma unroll
  for (int i = 0; i < 8; i++)
    pranks[((size_t)row * 16 + c) * SEQ + i * 256 + tid] = p[i];
}

// ---------------- top-k stage 2: sum partials, ballot-scan, emit ----------------
__global__ __launch_bounds__(1024) void topk_select(const float* __restrict__ scores,
    const int* __restrict__ pranks, int* __restrict__ sel, float* __restrict__ gates) {
  int bn = blockIdx.x;
  __shared__ int wsum[16];
  int tid = threadIdx.x;
  int t0 = tid * 2;
  int r0 = 0, r1 = 0;
#pragma unroll
  for (int c = 0; c < 16; c++) {
    const int2 pp = *(const int2*)&pranks[((size_t)bn * 16 + c) * SEQ + t0];
    r0 += pp.x; r1 += pp.y;
  }
  int f0 = r0 < KSEL, f1 = r1 < KSEL;
  unsigned long long b0 = __ballot(f0), b1 = __ballot(f1);
  int lane = tid & 63, wv = tid >> 6;
  unsigned long long lower = (1ULL << lane) - 1ULL;
  int before = __popcll(b0 & lower) + __popcll(b1 & lower);
  int wtotal = __popcll(b0) + __popcll(b1);
  if (lane == 0) wsum[wv] = wtotal;
  __syncthreads();
  int woff = 0;
#pragma unroll
  for (int i2 = 0; i2 < 16; i2++) woff += (i2 < wv) ? wsum[i2] : 0;
  int base = woff + before;
  if (f0) { sel[bn * KSEL + base] = t0;
            gates[bn * KSEL + base] = 1.f / (1.f + __expf(-scores[(size_t)bn * SEQ + t0]));
            base++; }
  if (f1) { sel[bn * KSEL + base] = t0 + 1;
            gates[bn * KSEL + base] = 1.f / (1.f + __expf(-scores[(size_t)bn * SEQ + t0 + 1])); }
}

// ---------------- mosa qkv: gathered-A bf16 MFMA GEMM, fused RoPE -> split layouts ------
__global__ __launch_bounds__(256) void gemm_mosa_bf16(const ushort* __restrict__ Xb,
    const ushort* __restrict__ Wt, const int* __restrict__ sel,
    ushort* __restrict__ Qmg, ushort* __restrict__ Kmg, ushort* __restrict__ Vtmg) {
  __shared__ __align__(16) ushort As[64][40];
  __shared__ __align__(16) ushort Bs[64][40];
  int bn = blockIdx.x;
  int m0 = blockIdx.y * 64, n0 = blockIdx.z * 64;
  int b = bn >> 3, n = bn & 7;
  int tid = threadIdx.x;
  int lane = tid & 63, w = tid >> 6;
  int wm = w & 1, wn = w >> 1;
  int cc = lane & 15, quad = lane >> 4;
  int sr = tid >> 2, sc4 = tid & 3;

  int grow = sel[bn * KSEL + m0 + sr];
  const ushort* arow = Xb + ((size_t)(b * SEQ) + grow) * HD;
  const ushort* brow = Wt + ((size_t)(n * D3 + n0 + sr)) * HD;

  f32x4 acc[2][2];
#pragma unroll
  for (int i = 0; i < 2; i++)
#pragma unroll
    for (int j = 0; j < 2; j++)
#pragma unroll
      for (int r = 0; r < 4; r++) acc[i][j][r] = 0.f;

  for (int k0 = 0; k0 < HD; k0 += 32) {
    __syncthreads();
    *(short8*)&As[sr][8 * sc4] = *(const short8*)(arow + k0 + 8 * sc4);
    *(short8*)&Bs[sr][8 * sc4] = *(const short8*)(brow + k0 + 8 * sc4);
    __syncthreads();
    short8 af[2], bf_[2];
#pragma unroll
    for (int i = 0; i < 2; i++) af[i] = *(const short8*)&As[32 * wm + 16 * i + cc][8 * quad];
#pragma unroll
    for (int j = 0; j < 2; j++) bf_[j] = *(const short8*)&Bs[32 * wn + 16 * j + cc][8 * quad];
#pragma unroll
    for (int i = 0; i < 2; i++)
#pragma unroll
      for (int j = 0; j < 2; j++)
        acc[i][j] = __builtin_amdgcn_mfma_f32_16x16x32_bf16(af[i], bf_[j], acc[i][j], 0, 0, 0);
  }

  int bs = n0 + 32 * wn;                 // band start: 0(Qrot),32,64(Krot),96,128+,160
  if (bs == 0 || bs == 64) {
    float inv = __expf((float)cc * ROPE_C);
#pragma unroll
    for (int i = 0; i < 2; i++) {
      int row0 = m0 + 32 * wm + 16 * i + 4 * quad;
#pragma unroll
      for (int r = 0; r < 4; r++) {
        float pos = (float)sel[bn * KSEL + row0 + r];
        float ang = pos * inv;
        float cs = cosf(ang), sn = sinf(ang);
        float x1 = acc[i][0][r], x2 = acc[i][1][r];
        acc[i][0][r] = x1 * cs - x2 * sn;
        acc[i][1][r] = x1 * sn + x2 * cs;
      }
    }
  }

#pragma unroll
  for (int i = 0; i < 2; i++)
#pragma unroll
    for (int j = 0; j < 2; j++) {
      int col = bs + 16 * j + cc;
      int row0 = m0 + 32 * wm + 16 * i + 4 * quad;
      if (col < 64) {
#pragma unroll
        for (int r = 0; r < 4; r++)
          Qmg[((size_t)bn * KSEL + row0 + r) * 64 + col] = bf16u(acc[i][j][r] * 0.125f);
      } else if (col < 128) {
#pragma unroll
        for (int r = 0; r < 4; r++)
          Kmg[((size_t)bn * KSEL + row0 + r) * 64 + (col - 64)] = bf16u(acc[i][j][r]);
      } else {
        ushort4 pk;
        pk.x = bf16u(acc[i][j][0]); pk.y = bf16u(acc[i][j][1]);
        pk.z = bf16u(acc[i][j][2]); pk.w = bf16u(acc[i][j][3]);
        *(ushort4*)&Vtmg[((size_t)bn * 64 + (col - 128)) * KSEL + row0] = pk;
      }
    }
}

// ---------------- flash6: split-K flash attention ----------------
__global__ __launch_bounds__(256) void flash6(
    const ushort* __restrict__ Qg, const ushort* __restrict__ Kg,
    const ushort* __restrict__ Vtg,
    const ushort* __restrict__ Qmg, const ushort* __restrict__ Kmg,
    const ushort* __restrict__ Vtmg,
    const int* __restrict__ sel, const float* __restrict__ gates,
    ushort* __restrict__ Opart, float2* __restrict__ Mlp,
    ushort* __restrict__ avm) {
  __shared__ __align__(16) ushort Ks[2][64][64];
  __shared__ __align__(16) ushort Vt[2][64][64];
  __shared__ __align__(16) ushort Ps[64][64];

  int bx = blockIdx.x;
  bool mosa = bx >= 2048;
  int bn, qt, T, kstart, kstride;
  const ushort *Qb, *Kb, *Vb;
  if (!mosa) {
    bn = bx & 15; qt = (bx >> 4) & 31;
    kstart = bx >> 9; kstride = 4; T = SEQ;
    Qb = Qg + (size_t)bn * SEQ * 64;
    Kb = Kg + (size_t)bn * SEQ * 64;
    Vb = Vtg + (size_t)bn * 64 * SEQ;
  } else {
    int rr = bx - 2048;
    bn = rr & 15; qt = 3 - (rr >> 4);
    kstart = 0; kstride = 1; T = KSEL;
    Qb = Qmg + (size_t)bn * KSEL * 64;
    Kb = Kmg + (size_t)bn * KSEL * 64;
    Vb = Vtmg + (size_t)bn * 64 * KSEL;
  }
  int b = bn >> 3, n = bn & 7;
  int tid = threadIdx.x;
  int lane = tid & 63, w = tid >> 6;
  int cc = lane & 15, quad = lane >> 4;
  int qrow = 16 * w + cc;

  short8 bq[2];
  {
    const ushort* qsrc = Qb + (size_t)(qt * 64 + qrow) * 64;
    bq[0] = *(const short8*)(qsrc + 8 * quad);
    bq[1] = *(const short8*)(qsrc + 8 * (quad + 4));
  }

  int rloc = lane >> 3;
  int c_log = (lane & 7) ^ rloc;
  int row0 = 16 * w + rloc, row1 = row0 + 8;
  const ushort* pK0 = Kb + (size_t)row0 * 64 + 8 * c_log;
  const ushort* pK1 = Kb + (size_t)row1 * 64 + 8 * c_log;
  const ushort* pV0 = Vb + (size_t)row0 * T + 8 * c_log;
  const ushort* pV1 = Vb + (size_t)row1 * T + 8 * c_log;

  f32x4 oacc[4];
  float m = NEG, l = 0.f;
#pragma unroll
  for (int jd = 0; jd < 4; jd++)
#pragma unroll
    for (int r = 0; r < 4; r++) oacc[jd][r] = 0.f;

  if (kstart <= qt) {
    gl_lds16(pK0 + (size_t)kstart * 4096, &Ks[0][16 * w][0]);
    gl_lds16(pK1 + (size_t)kstart * 4096, &Ks[0][16 * w + 8][0]);
    gl_lds16(pV0 + kstart * 64, &Vt[0][16 * w][0]);
    gl_lds16(pV1 + kstart * 64, &Vt[0][16 * w + 8][0]);
  }

  int it = 0;
  for (int kt = kstart; kt <= qt; kt += kstride, it++) {
    int buf = it & 1;
    __syncthreads();
    int nk = kt + kstride;
    if (nk <= qt) {
      int nb = buf ^ 1;
      gl_lds16(pK0 + (size_t)nk * 4096, &Ks[nb][16 * w][0]);
      gl_lds16(pK1 + (size_t)nk * 4096, &Ks[nb][16 * w + 8][0]);
      gl_lds16(pV0 + nk * 64, &Vt[nb][16 * w][0]);
      gl_lds16(pV1 + nk * 64, &Vt[nb][16 * w + 8][0]);
    }

    f32x4 sacc[4];
#pragma unroll
    for (int j = 0; j < 4; j++)
#pragma unroll
      for (int r = 0; r < 4; r++) sacc[j][r] = 0.f;
#pragma unroll
    for (int ks = 0; ks < 2; ks++) {
#pragma unroll
      for (int j = 0; j < 4; j++) {
        int krow = 16 * j + cc;
        short8 ak = *(const short8*)&Ks[buf][krow][8 * ((quad + 4 * ks) ^ (krow & 7))];
        sacc[j] = __builtin_amdgcn_mfma_f32_16x16x32_bf16(ak, bq[ks], sacc[j], 0, 0, 0);
      }
    }
    if (kt == qt) {
#pragma unroll
      for (int j = 0; j < 4; j++)
#pragma unroll
        for (int r = 0; r < 4; r++)
          if (16 * j + 4 * quad + r > qrow) sacc[j][r] = NEG;
    }
    float mx = NEG;
#pragma unroll
    for (int j = 0; j < 4; j++)
#pragma unroll
      for (int r = 0; r < 4; r++) mx = fmaxf(mx, sacc[j][r]);
    mx = fmaxf(mx, __shfl_xor(mx, 16));
    mx = fmaxf(mx, __shfl_xor(mx, 32));
    float mn = fmaxf(m, mx);
    float sc = __expf(m - mn);
    m = mn;
    float rsum = 0.f;
    float p[4][4];
#pragma unroll
    for (int j = 0; j < 4; j++)
#pragma unroll
      for (int r = 0; r < 4; r++) { p[j][r] = __expf(sacc[j][r] - mn); rsum += p[j][r]; }
    rsum += __shfl_xor(rsum, 16);
    rsum += __shfl_xor(rsum, 32);
    l = l * sc + rsum;
#pragma unroll
    for (int j = 0; j < 4; j++) {
      ushort4 pk;
      pk.x = bf16u(p[j][0]); pk.y = bf16u(p[j][1]);
      pk.z = bf16u(p[j][2]); pk.w = bf16u(p[j][3]);
      int phys = (2 * j + (quad >> 1)) ^ (qrow & 7);
      *(ushort4*)&Ps[qrow][phys * 8 + 4 * (quad & 1)] = pk;
    }
#pragma unroll
    for (int r = 0; r < 4; r++) {
      float scr = __shfl(sc, 16 * quad + 4 * quad + r);
#pragma unroll
      for (int jd = 0; jd < 4; jd++) oacc[jd][r] *= scr;
    }
    __asm__ volatile("s_waitcnt lgkmcnt(0)" ::: "memory");
#pragma unroll
    for (int ks = 0; ks < 2; ks++) {
      short8 ap = *(const short8*)&Ps[qrow][8 * ((quad + 4 * ks) ^ (qrow & 7))];
#pragma unroll
      for (int jd = 0; jd < 4; jd++) {
        int vrow = 16 * jd + cc;
        short8 bv = *(const short8*)&Vt[buf][vrow][8 * ((quad + 4 * ks) ^ (vrow & 7))];
        oacc[jd] = __builtin_amdgcn_mfma_f32_16x16x32_bf16(ap, bv, oacc[jd], 0, 0, 0);
      }
    }
  }

  if (!mosa) {
    size_t pb = ((size_t)(bn * 32 + qt) * 4 + (size_t)(kstart));
    ushort* obase = Opart + pb * 4096;
#pragma unroll
    for (int r = 0; r < 4; r++) {
      int ql = 16 * w + 4 * quad + r;
#pragma unroll
      for (int jd = 0; jd < 4; jd++)
        obase[ql * 64 + 16 * jd + cc] = bf16u(oacc[jd][r]);
    }
    if (quad == 0) Mlp[pb * 64 + qrow] = make_float2(m, l);
  } else {
#pragma unroll
    for (int r = 0; r < 4; r++) {
      float lr = __shfl(l, 16 * quad + 4 * quad + r);
      int q = qt * 64 + 16 * w + 4 * quad + r;
      int trow = sel[bn * KSEL + q];
      float scale = gates[bn * KSEL + q] / lr;
      size_t row = (size_t)(b * SEQ + trow);
      ushort* orow = avm + row * (NHEAD * DH) + n * DH;
#pragma unroll
      for (int jd = 0; jd < 4; jd++)
        orow[16 * jd + cc] = bf16u(oacc[jd][r] * scale);
    }
  }
}

// ---------------- merge 4 split-K partials -> avd ----------------
__global__ __launch_bounds__(256) void flash_merge(const ushort* __restrict__ Opart,
    const float2* __restrict__ Mlp, ushort* __restrict__ avd) {
  int bq = blockIdx.x;            // bn*32 + qt
  int bn = bq >> 5, qt = bq & 31;
  int b = bn >> 3, n = bn & 7;
  int tid = threadIdx.x;
  int q = tid >> 2, ds = (tid & 3) * 16;
  size_t pb = (size_t)bq * 4;
  float2 ml[4];
#pragma unroll
  for (int c = 0; c < 4; c++) ml[c] = Mlp[(pb + c) * 64 + q];
  float M = fmaxf(fmaxf(ml[0].x, ml[1].x), fmaxf(ml[2].x, ml[3].x));
  float wgt[4], L = 0.f;
#pragma unroll
  for (int c = 0; c < 4; c++) { wgt[c] = __expf(ml[c].x - M); L += wgt[c] * ml[c].y; }
  float inv = 1.f / L;
  float acc[16] = {};
#pragma unroll
  for (int c = 0; c < 4; c++) {
    const ushort* op = Opart + (pb + c) * 4096 + q * 64 + ds;
    short8 v0 = *(const short8*)op;
    short8 v1 = *(const short8*)(op + 8);
#pragma unroll
    for (int d = 0; d < 8; d++) acc[d] += wgt[c] * bf2f(((const ushort*)&v0)[d]);
#pragma unroll
    for (int d = 0; d < 8; d++) acc[8 + d] += wgt[c] * bf2f(((const ushort*)&v1)[d]);
  }
  ushort* orow = avd + ((size_t)(b * SEQ + qt * 64 + q)) * (NHEAD * DH) + n * DH + ds;
#pragma unroll
  for (int d = 0; d < 16; d++) orow[d] = bf16u(acc[d] * inv);
}

// ---------------- bf16 MFMA GEMM, async gl_lds staging ----------------
// MODE 0: 128x128 tile, out f32 = A1@B1 + A2@B2 (grid 32x8 = 1/CU exact).
// MODE 1: 64x128 tile (grid 64x12 = 768 = 3/CU exact), dense-qkv + fused RoPE.
template <int MODE>
__global__ __launch_bounds__(256) void gemm_bf16(
    const ushort* __restrict__ A1, const ushort* __restrict__ B1t, int K1,
    const ushort* __restrict__ A2, const ushort* __restrict__ B2t, int K2,
    void* __restrict__ outv, int N,
    ushort* __restrict__ Qo, ushort* __restrict__ Ko, ushort* __restrict__ Vto) {
  constexpr int TM = (MODE == 1) ? 64 : 128;
  constexpr int WI = TM / 32;                    // i-frags per wave
  __shared__ __align__(16) ushort As[TM][32];
  __shared__ __align__(16) ushort Bs[128][32];
  int m0 = blockIdx.x * TM, n0 = blockIdx.y * 128;
  int tid = threadIdx.x;
  int lane = tid & 63, wave = tid >> 6;
  int wm = wave & 1, wn = wave >> 1;
  int cc = lane & 15, quad = lane >> 4;

  int srow = 16 * wave + (lane >> 2);            // 0..63
  int c_log = ((lane & 3) - (lane >> 3)) & 3;

  f32x4 acc[WI][4];
#pragma unroll
  for (int i = 0; i < WI; i++)
#pragma unroll
    for (int j = 0; j < 4; j++)
#pragma unroll
      for (int r = 0; r < 4; r++) acc[i][j][r] = 0.f;

  const int npass = (MODE == 0) ? 2 : 1;
  for (int pass = 0; pass < npass; pass++) {
    const ushort* A = pass ? A2 : A1;
    const ushort* Bt = pass ? B2t : B1t;
    int K = pass ? K2 : K1;
    const ushort* pA0 = A + (size_t)(m0 + srow) * K + 8 * c_log;
    const ushort* pA1 = A + (size_t)(m0 + srow + (TM == 128 ? 64 : 0)) * K + 8 * c_log;
    const ushort* pB0 = Bt + (size_t)(n0 + srow) * K + 8 * c_log;
    const ushort* pB1 = Bt + (size_t)(n0 + srow + 64) * K + 8 * c_log;
    for (int k0 = 0; k0 < K; k0 += 32) {
      __syncthreads();
      gl_lds16(pA0 + k0, &As[16 * wave][0]);
      if (TM == 128) gl_lds16(pA1 + k0, &As[(16 * wave + 64) % TM][0]);
      gl_lds16(pB0 + k0, &Bs[16 * wave][0]);
      gl_lds16(pB1 + k0, &Bs[16 * wave + 64][0]);
      __syncthreads();
      short8 af[WI], bfr[4];
#pragma unroll
      for (int i = 0; i < WI; i++) {
        int ra = (TM / 2) * wm + 16 * i + cc;
        af[i] = *(const short8*)&As[ra][8 * ((quad + (ra >> 1)) & 3)];
      }
#pragma unroll
      for (int j = 0; j < 4; j++) {
        int rb = 64 * wn + 16 * j + cc;
        bfr[j] = *(const short8*)&Bs[rb][8 * ((quad + (rb >> 1)) & 3)];
      }
#pragma unroll
      for (int i = 0; i < WI; i++)
#pragma unroll
        for (int j = 0; j < 4; j++)
          acc[i][j] = __builtin_amdgcn_mfma_f32_16x16x32_bf16(af[i], bfr[j], acc[i][j], 0, 0, 0);
    }
  }

  if (MODE == 1) {
    // fused RoPE: band start bs=(n0+64*wn)%192 in {0(Q),64(K),128(V)};
    // pair = (acc[i][0], acc[i][1]) = dims (cc, cc+16); pos = t = row & 2047
    int bs = (n0 + 64 * wn) % 192;
    if (bs < 128) {
      float inv = __expf((float)cc * ROPE_C);
#pragma unroll
      for (int i = 0; i < WI; i++) {
        int row0 = m0 + (TM / 2) * wm + 16 * i + 4 * quad;
#pragma unroll
        for (int r = 0; r < 4; r++) {
          float pos = (float)((row0 + r) & (SEQ - 1));
          float ang = pos * inv;
          float cs = cosf(ang), sn = sinf(ang);
          float x1 = acc[i][0][r], x2 = acc[i][1][r];
          acc[i][0][r] = x1 * cs - x2 * sn;
          acc[i][1][r] = x1 * sn + x2 * cs;
        }
      }
    }
  }

#pragma unroll
  for (int i = 0; i < WI; i++) {
#pragma unroll
    for (int j = 0; j < 4; j++) {
      int colg = n0 + 64 * wn + 16 * j + cc;
      int row0 = m0 + (TM / 2) * wm + 16 * i + 4 * quad;
      if (MODE == 0) {
#pragma unroll
        for (int r = 0; r < 4; r++)
          ((float*)outv)[(size_t)(row0 + r) * N + colg] = acc[i][j][r];
      } else {
        int nn = colg / 192, c = colg % 192;
        int b2 = row0 >> 11, t2 = row0 & 2047;
        int bn2 = b2 * 8 + nn;
        if (c < 64) {
#pragma unroll
          for (int r = 0; r < 4; r++)
            Qo[((size_t)bn2 * SEQ + t2 + r) * 64 + c] = bf16u(acc[i][j][r] * 0.125f);
        } else if (c < 128) {
#pragma unroll
          for (int r = 0; r < 4; r++)
            Ko[((size_t)bn2 * SEQ + t2 + r) * 64 + (c - 64)] = bf16u(acc[i][j][r]);
        } else {
          ushort4 pk;
          pk.x = bf16u(acc[i][j][0]); pk.y = bf16u(acc[i][j][1]);
          pk.z = bf16u(acc[i][j][2]); pk.w = bf16u(acc[i][j][3]);
          *(ushort4*)&Vto[((size_t)bn2 * 64 + (c - 128)) * SEQ + t2] = pk;
        }
      }
    }
  }
}

extern "C" void kernel_launch(void* const* d_in, const int* in_sizes, int n_in,
                              void* d_out, int out_size, void* d_ws, size_t ws_size,
                              hipStream_t stream) {
  const float* X          = (const float*)d_in[0];
  const float* router_w   = (const float*)d_in[1];
  const float* mosa_wqkv  = (const float*)d_in[2];
  const float* mosa_wo    = (const float*)d_in[3];
  const float* dense_wqkv = (const float*)d_in[4];
  const float* dense_wo   = (const float*)d_in[5];
  float* out = (float*)d_out;
  char* ws = (char*)d_ws;

  // workspace layout (bytes)
  float*  scores  = (float*) (ws + 0);          // 131072
  int*    sel     = (int*)   (ws + 131072);     // 16384
  float*  gates   = (float*) (ws + 147456);     // 16384
  ushort* avm     = (ushort*)(ws + 163840);     // 4194304
  ushort* avd     = (ushort*)(ws + 4358144);    // 4194304
  ushort* Xb      = (ushort*)(ws + 8552448);    // 8388608
  ushort* Wqkv_t  = (ushort*)(ws + 16941056);   // 3145728
  ushort* Wmq_t   = (ushort*)(ws + 20086784);   // 3145728
  ushort* Wdo_t   = (ushort*)(ws + 23232512);   // 1048576
  ushort* Wmo_t   = (ushort*)(ws + 24281088);   // 1048576
  ushort* Qg      = (ushort*)(ws + 25329664);   // 4194304  (16 bn x 2048 x 64)
  ushort* Kg      = (ushort*)(ws + 29523968);   // 4194304
  ushort* Vtg     = (ushort*)(ws + 33718272);   // 4194304  (16 bn x 64 x 2048)
  ushort* Qmg     = (ushort*)(ws + 37912576);   // 524288   (16 bn x 256 x 64)
  ushort* Kmg     = (ushort*)(ws + 38436864);   // 524288
  ushort* Vtmg    = (ushort*)(ws + 38961152);   // 524288
  int*    pranks  = (int*)   (ws + 39485440);   // 2097152
  ushort* Opart   = (ushort*)(ws + 41582592);   // 16777216
  float2* Mlp     = (float2*)(ws + 58359808);   // 2097152 (end 60456960)

  // fused X cast + router + avm zero; all 4 weight transposes in one launch
  cast_router<<<BB * SEQ / 32, 256, 0, stream>>>(X, router_w, Xb, scores, avm);
  transpose_cast4<<<dim3(48, 32, 4), 256, 0, stream>>>(
      dense_wqkv, Wqkv_t, mosa_wqkv, Wmq_t, dense_wo, Wdo_t, mosa_wo, Wmo_t);

  // top-k
  topk_partial<<<dim3(BB * NHEAD, 16), 256, 0, stream>>>(scores, pranks);
  topk_select<<<BB * NHEAD, 1024, 0, stream>>>(scores, pranks, sel, gates);

  // qkv projections with fused RoPE (mosa gathered + dense)
  gemm_mosa_bf16<<<dim3(BB * NHEAD, KSEL / 64, D3 / 64), 256, 0, stream>>>(
      Xb, Wmq_t, sel, Qmg, Kmg, Vtmg);
  gemm_bf16<1><<<dim3(64, 12), 256, 0, stream>>>(Xb, Wqkv_t, 1024,
      (const ushort*)nullptr, (const ushort*)nullptr, 0, nullptr, NHEAD * D3,
      Qg, Kg, Vtg);

  // split-K flash attention (dense 2048 chunk-blocks + mosa 64) + merge
  flash6<<<2112, 256, 0, stream>>>(Qg, Kg, Vtg, Qmg, Kmg, Vtmg, sel, gates,
                                   Opart, Mlp, avm);
  flash_merge<<<512, 256, 0, stream>>>(Opart, Mlp, avd);

  // final: out = avm@mosa_wo + avd@dense_wo  (f32 out)
  gemm_bf16<0><<<dim3(32, 8), 256, 0, stream>>>(avm, Wmo_t, 512, avd, Wdo_t, 512, out, HD,
                                                nullptr, nullptr, nullptr);
}